// Round 9
// baseline (468.216 us; speedup 1.0000x reference)
//
#include <hip/hip_runtime.h>

// BitLinear: out[b,t,o] = scale_x[b,t] * scale_w * sum_d qx[b,t,d] * tw[o,d]
// qx = clip(round(127*x/(max|x|row + eps)), -128, 127)   (int8, exact)
// tw = clip(round(w/(mean|W| + eps)), -1, 1)             (ternary, exact)
// Integer GEMM via mfma_i32_16x16x64_i8, fp32 dequant epilogue.
// R9: geometry rebalance. BM=256 BN=128 BK=64, 8 waves (4Mx2N), wave tile
// 64x64 (acc=64 VGPR -> ~110 total -> 4 waves/SIMD), LDS 48 KiB -> 2
// blocks/CU (cross-block overlap of barriers+epilogue). LDS uses a
// paired-row layout (128-B srow = 2 logical 64-B rows) with 8-slot XOR
// swizzle == R6's verified bank pattern. 4-phase/iter schedule, vmcnt(1)
// gates at p2/p4 (ledger re-derived, see comments).

#define M_ROWS 4096   // B*T
#define K_DIM  4096   // D_IN
#define N_DIM  16384  // D_OUT
#define W_ELEMS (N_DIM * K_DIM)          // 67108864
#define EPSF 1e-8f

using i32x4 = __attribute__((ext_vector_type(4))) int;

// ---------- kernel 1: |W| partial sums (deterministic) ----------
__global__ void k_abs_partial(const float4* __restrict__ w4,
                              double* __restrict__ part) {
    const int tid = threadIdx.x;
    int idx = blockIdx.x * 256 + tid;
    double s = 0.0;
    #pragma unroll 4
    for (int it = 0; it < 32; ++it) {
        float4 v = w4[idx + it * (2048 * 256)];
        s += (double)fabsf(v.x) + (double)fabsf(v.y)
           + (double)fabsf(v.z) + (double)fabsf(v.w);
    }
    __shared__ double red[256];
    red[tid] = s;
    __syncthreads();
    for (int o = 128; o > 0; o >>= 1) {
        if (tid < o) red[tid] += red[tid + o];
        __syncthreads();
    }
    if (tid == 0) part[blockIdx.x] = red[0];
}

__global__ void k_abs_final(const double* __restrict__ part,
                            float* __restrict__ scales) {
    const int tid = threadIdx.x;
    double s = 0.0;
    #pragma unroll
    for (int k = 0; k < 8; ++k) s += part[tid + k * 256];
    __shared__ double red[256];
    red[tid] = s;
    __syncthreads();
    for (int o = 128; o > 0; o >>= 1) {
        if (tid < o) red[tid] += red[tid + o];
        __syncthreads();
    }
    if (tid == 0) {
        float sw = (float)(red[0] / (double)W_ELEMS);
        scales[0] = sw;
        scales[1] = sw + EPSF;
    }
}

// ---------- kernel 2: ternary weight quant ----------
__global__ void k_wquant(const float4* __restrict__ w4,
                         const float* __restrict__ scales,
                         char4* __restrict__ wq4) {
    const float seps = scales[1];
    int idx = blockIdx.x * 256 + threadIdx.x;
    const int stride = 8192 * 256;
    #pragma unroll
    for (int it = 0; it < 8; ++it) {
        int i = idx + it * stride;
        float4 v = w4[i];
        char4 q;
        q.x = (signed char)(int)fminf(fmaxf(rintf(v.x / seps), -1.0f), 1.0f);
        q.y = (signed char)(int)fminf(fmaxf(rintf(v.y / seps), -1.0f), 1.0f);
        q.z = (signed char)(int)fminf(fmaxf(rintf(v.z / seps), -1.0f), 1.0f);
        q.w = (signed char)(int)fminf(fmaxf(rintf(v.w / seps), -1.0f), 1.0f);
        wq4[i] = q;
    }
}

// ---------- kernel 3: per-token int8 activation quant ----------
__global__ void k_xquant(const float4* __restrict__ x4,
                         char4* __restrict__ xq4,
                         float* __restrict__ sx) {
    const int row = blockIdx.x, tid = threadIdx.x;
    const float4* xr = x4 + (size_t)row * (K_DIM / 4);
    float4 v[4];
    float m = 0.0f;
    #pragma unroll
    for (int j = 0; j < 4; ++j) {
        v[j] = xr[tid + j * 256];
        m = fmaxf(m, fmaxf(fmaxf(fabsf(v[j].x), fabsf(v[j].y)),
                           fmaxf(fabsf(v[j].z), fabsf(v[j].w))));
    }
    __shared__ float red[256];
    red[tid] = m;
    __syncthreads();
    for (int o = 128; o > 0; o >>= 1) {
        if (tid < o) red[tid] = fmaxf(red[tid], red[tid + o]);
        __syncthreads();
    }
    const float gamma = red[0];
    const float ge = gamma + EPSF;
    char4* out = xq4 + (size_t)row * (K_DIM / 4);
    #pragma unroll
    for (int j = 0; j < 4; ++j) {
        char4 q;
        q.x = (signed char)(int)fminf(fmaxf(rintf(127.0f * v[j].x / ge), -128.0f), 127.0f);
        q.y = (signed char)(int)fminf(fmaxf(rintf(127.0f * v[j].y / ge), -128.0f), 127.0f);
        q.z = (signed char)(int)fminf(fmaxf(rintf(127.0f * v[j].z / ge), -128.0f), 127.0f);
        q.w = (signed char)(int)fminf(fmaxf(rintf(127.0f * v[j].w / ge), -128.0f), 127.0f);
        out[tid + j * 256] = q;
    }
    if (tid == 0) sx[row] = gamma / 127.0f;
}

// ---------- kernel 4: int8 GEMM, 256x128 tile, BK=64, 4-phase ----------
__device__ __forceinline__ void gload16(const signed char* g, signed char* l) {
    __builtin_amdgcn_global_load_lds(
        (const __attribute__((address_space(1))) void*)g,
        (__attribute__((address_space(3))) void*)l, 16, 0, 0);
}

#define BAR()   __builtin_amdgcn_s_barrier()
#define VM1()   asm volatile("s_waitcnt vmcnt(1)" ::: "memory")
#define PRIO1() __builtin_amdgcn_s_setprio(1)
#define PRIO0() __builtin_amdgcn_s_setprio(0)
#define SCHED0() __builtin_amdgcn_sched_barrier(0)

// LDS paired-row layout (per buf: A 16 KiB + B 8 KiB; 2 bufs = 48 KiB):
// logical (row r, 16-B chunk c in 0..3) stored at
//   (r>>1)*128 + ((( r&1)*4 + c) ^ ((r>>1)&7)) * 16
// Fragment read (16-lane group, rows base+l15, chunk qg): per-lane slot
// ((l15&1)*4+qg)^(l15>>1) -> each 16-B slot hit by exactly 2 lanes (free).
// Staging: thread t covers LDS byte t*16 of an 8-KiB region ->
//   srow=t>>3, slotd=(t&7)^(srow&7), relrow=2*srow+(slotd>>2), chunk=slotd&3.
//
// Schedule per iter t (buf0=k0=2t, buf1=k1=2t+1; k2=2t+2, k3=2t+3):
//  p1: rd A(b0),B01(b0) | stg A2(b1,k1), B(b1,k1) | BAR MFMA(b0,fn01) rd@e B23(b0) BAR
//  p2: stg A1(b0,k2)                              | BAR MFMA(b0,fn23) VM1 BAR
//  p3: rd A(b1),B01(b1) | stg A2(b0,k2), B(b0,k2) | BAR MFMA(b1,fn01) rd@e B23(b1) BAR
//  p4: stg A1(b1,k3)                              | BAR MFMA(b1,fn23) VM1 BAR
// Gate ledger: p2's VM1 completes {A1(b1,k1) from prev p4, A2+B(b1,k1) from
// p1} = buf1 complete before p3 reads (after BAR). p4's VM1 completes
// {A1(b0,k2), A2+B(b0,k2)} = buf0 complete before next p1. Each stage
// issues >=1 barrier after its region's last read was drained (audited).
// Prologue: A1,A2,B(b0,k0) + A1(b1,k1); VM1 -> b0 complete; BAR.
__global__ __launch_bounds__(512, 4)
void k_gemm8(const signed char* __restrict__ Aq,   // [4096][4096]  (M x K)
             const signed char* __restrict__ Bq,   // [16384][4096] (N x K)
             const float* __restrict__ sx,
             const float* __restrict__ scales,
             float* __restrict__ C) {
    __shared__ __align__(16) signed char lds[49152];

    const int tid  = threadIdx.x;
    const int lane = tid & 63;
    const int wid  = tid >> 6;
    const int l15  = lane & 15;
    const int qg   = lane >> 4;

    // XCD-bijective swizzle (nwg=2048 % 8 == 0) + supergroup-of-8-pm mapping
    const int bid = blockIdx.x;
    const int wg  = (bid & 7) * 256 + (bid >> 3);
    const int gidx   = wg >> 10;              // 8 pm x 128 pn = 1024/group
    const int within = wg & 1023;
    const int pm = gidx * 8 + (within & 7);   // [0,16)
    const int pn = within >> 3;               // [0,128)

    const int wm = (wid >> 1) * 64;           // 4 M-waves
    const int wn = (wid & 1) * 64;            // 2 N-waves

    // ---- staging source mapping (paired-row layout) ----
    const int srow  = tid >> 3;
    const int slotd = (tid & 7) ^ (srow & 7);
    const int relrow = 2 * srow + (slotd >> 2);
    const int lane_off = relrow * K_DIM + (slotd & 3) * 16;
    const signed char* Asrc = Aq + (size_t)(pm * 256) * K_DIM + lane_off;
    const signed char* Bsrc = Bq + (size_t)(pn * 128) * K_DIM + lane_off;
    signed char* const dA = lds + wid * 1024;          // + buf*24576 + h*8192
    signed char* const dB = lds + 16384 + wid * 1024;  // + buf*24576

    auto stageA = [&](int buf, int h, int kt) {
        gload16(Asrc + (size_t)(h * 128) * K_DIM + kt * 64,
                dA + buf * 24576 + h * 8192);
    };
    auto stageB = [&](int buf, int kt) {
        gload16(Bsrc + kt * 64, dB + buf * 24576);
    };

    i32x4 acc[4][4];
    #pragma unroll
    for (int a = 0; a < 4; ++a)
        #pragma unroll
        for (int b = 0; b < 4; ++b)
            acc[a][b] = (i32x4){0, 0, 0, 0};

    // fragment read addressing: slot per-lane constant
    const int slotf = (((l15 & 1) << 2) + qg) ^ (l15 >> 1);
    const int froff = (l15 >> 1) * 128 + slotf * 16;

    i32x4 af[4], bf[4];
    auto ldA = [&](int buf) {
        const signed char* base = lds + buf * 24576 + wm * 64 + froff;
        #pragma unroll
        for (int fm = 0; fm < 4; ++fm)
            af[fm] = *(const i32x4*)(base + fm * 1024);   // 16 rows = 1024 B
    };
    auto ldB2 = [&](int buf, int half) {
        const signed char* base = lds + buf * 24576 + 16384 + wn * 64 + froff;
        #pragma unroll
        for (int f = 0; f < 2; ++f)
            bf[half * 2 + f] = *(const i32x4*)(base + (half * 2 + f) * 1024);
    };
    auto mma2 = [&](int half) {
        #pragma unroll
        for (int fm = 0; fm < 4; ++fm)
            #pragma unroll
            for (int f = 0; f < 2; ++f)
                acc[fm][half * 2 + f] = __builtin_amdgcn_mfma_i32_16x16x64_i8(
                    af[fm], bf[half * 2 + f], acc[fm][half * 2 + f], 0, 0, 0);
    };

    // ---- prologue ----
    stageA(0, 0, 0); stageA(0, 1, 0); stageB(0, 0);
    stageA(1, 0, 1);
    VM1();   // drain 3 oldest = buf0 complete; A1(b1,k1) in flight
    BAR();

    // ---- main loop: 32 iters x 2 K-steps ----
    for (int t = 0; t < 32; ++t) {
        const int k1 = 2 * t + 1;
        const int k2 = (2 * t + 2) & 63;   // wrap: harmless garbage stage
        const int k3 = (2 * t + 3) & 63;

        // p1: MFMA(b0, fn01)
        ldA(0); ldB2(0, 0);
        stageA(1, 1, k1); stageB(1, k1);
        BAR(); PRIO1(); mma2(0); PRIO0(); SCHED0();
        ldB2(0, 1); SCHED0();
        BAR();
        // p2: MFMA(b0, fn23) | GATE -> buf1 (k1) complete after BAR
        stageA(0, 0, k2);
        BAR(); PRIO1(); mma2(1); PRIO0(); SCHED0();
        VM1();
        BAR();
        // p3: MFMA(b1, fn01)
        ldA(1); ldB2(1, 0);
        stageA(0, 1, k2); stageB(0, k2);
        BAR(); PRIO1(); mma2(0); PRIO0(); SCHED0();
        ldB2(1, 1); SCHED0();
        BAR();
        // p4: MFMA(b1, fn23) | GATE -> buf0 (k2) complete after BAR
        stageA(1, 0, k3);
        BAR(); PRIO1(); mma2(1); PRIO0(); SCHED0();
        VM1();
        BAR();
    }
    asm volatile("s_waitcnt vmcnt(0)" ::: "memory");  // drain tail garbage stages

    // ---- epilogue: C/D frag: col=lane&15, row=(lane>>4)*4+reg ----
    const float sw = scales[0];
    const int gn0 = pn * 128 + wn + l15;
    const int rb  = qg * 4;
    #pragma unroll
    for (int fm = 0; fm < 4; ++fm) {
        #pragma unroll
        for (int r = 0; r < 4; ++r) {
            const int gm = pm * 256 + wm + fm * 16 + rb + r;
            const float s = sx[gm] * sw;
            float* crow = C + (size_t)gm * N_DIM + gn0;
            #pragma unroll
            for (int fn = 0; fn < 4; ++fn)
                crow[fn * 16] = (float)acc[fm][fn][r] * s;
        }
    }
}

extern "C" void kernel_launch(void* const* d_in, const int* in_sizes, int n_in,
                              void* d_out, int out_size, void* d_ws, size_t ws_size,
                              hipStream_t stream) {
    const float* x = (const float*)d_in[0];   // (2,2048,4096) f32
    const float* w = (const float*)d_in[1];   // (16384,4096) f32
    float* out = (float*)d_out;               // (2,2048,16384) f32
    char* ws = (char*)d_ws;

    float*  scales = (float*)(ws);                     // 2 floats
    double* part   = (double*)(ws + 1024);             // 2048 doubles
    float*  sx     = (float*)(ws + 32 * 1024);         // 4096 floats
    signed char* xq = (signed char*)(ws + 64 * 1024);  // 16 MiB
    signed char* wq = xq + (size_t)M_ROWS * K_DIM;     // 64 MiB

    k_abs_partial<<<2048, 256, 0, stream>>>((const float4*)w, part);
    k_abs_final<<<1, 256, 0, stream>>>(part, scales);
    k_wquant<<<8192, 256, 0, stream>>>((const float4*)w, scales, (char4*)wq);
    k_xquant<<<M_ROWS, 256, 0, stream>>>((const float4*)x, (char4*)xq, sx);
    k_gemm8<<<(M_ROWS / 256) * (N_DIM / 128), 512, 0, stream>>>(xq, wq, sx, scales, out);
}

// Round 10
// 407.404 us; speedup vs baseline: 1.1493x; 1.1493x over previous
//
#include <hip/hip_runtime.h>

// BitLinear: out[b,t,o] = scale_x[b,t] * scale_w * sum_d qx[b,t,d] * tw[o,d]
// qx = clip(round(127*x/(max|x|row + eps)), -128, 127)   (int8, exact)
// tw = clip(round(w/(mean|W| + eps)), -1, 1)             (ternary, exact)
// Integer GEMM via mfma_i32_16x16x64_i8, fp32 dequant epilogue.
// R10: R8 base (269us) with quadrant-phase pairs MERGED -> 4 phases/iter,
// 8 barriers/iter (was 16), same LDS traffic and registers. Stage
// assignment re-derived for merged windows (full audit in comments);
// gates use vmcnt(4) (12 outstanding -> drain 8 = the buffer read next).

#define M_ROWS 4096   // B*T
#define K_DIM  4096   // D_IN
#define N_DIM  16384  // D_OUT
#define W_ELEMS (N_DIM * K_DIM)          // 67108864
#define EPSF 1e-8f

using i32x4 = __attribute__((ext_vector_type(4))) int;

// ---------- kernel 1: |W| partial sums (deterministic) ----------
__global__ void k_abs_partial(const float4* __restrict__ w4,
                              double* __restrict__ part) {
    const int tid = threadIdx.x;
    int idx = blockIdx.x * 256 + tid;
    double s = 0.0;
    #pragma unroll 4
    for (int it = 0; it < 32; ++it) {
        float4 v = w4[idx + it * (2048 * 256)];
        s += (double)fabsf(v.x) + (double)fabsf(v.y)
           + (double)fabsf(v.z) + (double)fabsf(v.w);
    }
    __shared__ double red[256];
    red[tid] = s;
    __syncthreads();
    for (int o = 128; o > 0; o >>= 1) {
        if (tid < o) red[tid] += red[tid + o];
        __syncthreads();
    }
    if (tid == 0) part[blockIdx.x] = red[0];
}

__global__ void k_abs_final(const double* __restrict__ part,
                            float* __restrict__ scales) {
    const int tid = threadIdx.x;
    double s = 0.0;
    #pragma unroll
    for (int k = 0; k < 8; ++k) s += part[tid + k * 256];
    __shared__ double red[256];
    red[tid] = s;
    __syncthreads();
    for (int o = 128; o > 0; o >>= 1) {
        if (tid < o) red[tid] += red[tid + o];
        __syncthreads();
    }
    if (tid == 0) {
        float sw = (float)(red[0] / (double)W_ELEMS);
        scales[0] = sw;
        scales[1] = sw + EPSF;
    }
}

// ---------- kernel 2: ternary weight quant ----------
__global__ void k_wquant(const float4* __restrict__ w4,
                         const float* __restrict__ scales,
                         char4* __restrict__ wq4) {
    const float seps = scales[1];
    int idx = blockIdx.x * 256 + threadIdx.x;
    const int stride = 8192 * 256;
    #pragma unroll
    for (int it = 0; it < 8; ++it) {
        int i = idx + it * stride;
        float4 v = w4[i];
        char4 q;
        q.x = (signed char)(int)fminf(fmaxf(rintf(v.x / seps), -1.0f), 1.0f);
        q.y = (signed char)(int)fminf(fmaxf(rintf(v.y / seps), -1.0f), 1.0f);
        q.z = (signed char)(int)fminf(fmaxf(rintf(v.z / seps), -1.0f), 1.0f);
        q.w = (signed char)(int)fminf(fmaxf(rintf(v.w / seps), -1.0f), 1.0f);
        wq4[i] = q;
    }
}

// ---------- kernel 3: per-token int8 activation quant ----------
__global__ void k_xquant(const float4* __restrict__ x4,
                         char4* __restrict__ xq4,
                         float* __restrict__ sx) {
    const int row = blockIdx.x, tid = threadIdx.x;
    const float4* xr = x4 + (size_t)row * (K_DIM / 4);
    float4 v[4];
    float m = 0.0f;
    #pragma unroll
    for (int j = 0; j < 4; ++j) {
        v[j] = xr[tid + j * 256];
        m = fmaxf(m, fmaxf(fmaxf(fabsf(v[j].x), fabsf(v[j].y)),
                           fmaxf(fabsf(v[j].z), fabsf(v[j].w))));
    }
    __shared__ float red[256];
    red[tid] = m;
    __syncthreads();
    for (int o = 128; o > 0; o >>= 1) {
        if (tid < o) red[tid] = fmaxf(red[tid], red[tid + o]);
        __syncthreads();
    }
    const float gamma = red[0];
    const float ge = gamma + EPSF;
    char4* out = xq4 + (size_t)row * (K_DIM / 4);
    #pragma unroll
    for (int j = 0; j < 4; ++j) {
        char4 q;
        q.x = (signed char)(int)fminf(fmaxf(rintf(127.0f * v[j].x / ge), -128.0f), 127.0f);
        q.y = (signed char)(int)fminf(fmaxf(rintf(127.0f * v[j].y / ge), -128.0f), 127.0f);
        q.z = (signed char)(int)fminf(fmaxf(rintf(127.0f * v[j].z / ge), -128.0f), 127.0f);
        q.w = (signed char)(int)fminf(fmaxf(rintf(127.0f * v[j].w / ge), -128.0f), 127.0f);
        out[tid + j * 256] = q;
    }
    if (tid == 0) sx[row] = gamma / 127.0f;
}

// ---------- kernel 4: int8 GEMM, 256x256 tile, 4 merged phases ----------
__device__ __forceinline__ void gload16(const signed char* g, signed char* l) {
    __builtin_amdgcn_global_load_lds(
        (const __attribute__((address_space(1))) void*)g,
        (__attribute__((address_space(3))) void*)l, 16, 0, 0);
}

#define BAR()   __builtin_amdgcn_s_barrier()
#define VM4()   asm volatile("s_waitcnt vmcnt(4)" ::: "memory")
#define PRIO1() __builtin_amdgcn_s_setprio(1)
#define PRIO0() __builtin_amdgcn_s_setprio(0)
#define SCHED0() __builtin_amdgcn_sched_barrier(0)

// Geometry: BM=BN=256, BK=128 i8, 8 waves (2M x 4N), per-wave 128x64 out.
// LDS 128 KiB: 2 dbuf x (A 32K + B 32K), [256 rows][128 B], chunk-XOR swizzle
// LDS[row][c] = G[row][c ^ (row&7)] via pre-swizzled global source (rule #21).
//
// Merged phases (iter t; k1=2t+1, k2=2t+2, k3=2t+3). Phase =
//   {stages; pre-reads} BAR {cluster; mid-read; cluster} BAR
//  mp1: stg B1.nh0(k1),A1.mh1(k1) | pre ldA(0,0),ldB(0,0) | mma(0,0); ldB(0,1); mma(0,1)
//  mp2: stg A0.mh0(k2),B0.nh1(k2) | pre ldA(0,1)          | mma(1,1); ldB(0,0); mma(1,0) | VM4 GATE
//  mp3: stg A0.mh1(k2),B0.nh0(k2) | pre ldA(1,0),ldB(1,0) | mma(0,0); ldB(1,1); mma(0,1)
//  mp4: stg A1.mh0(k3),B1.nh1(k3) | pre ldA(1,1)          | mma(1,1); ldB(1,0); mma(1,0) | VM4 GATE
// Stage-after-read audit (region: last LDS read -> separating barrier):
//  B1.nh0(k1): mp4-mid prev iter -> mp4 close ✓   A1.mh1(k1): mp4-pre prev -> mp4 close ✓
//  A0.mh0(k2): mp1-pre -> mp1 close ✓             B0.nh1(k2): mp1-mid -> mp1 close ✓
//  A0.mh1(k2): mp2-pre -> mp2 close ✓             B0.nh0(k2): mp2-mid -> mp2 close ✓
//  A1.mh0(k3): mp3-pre -> mp3 close ✓             B1.nh1(k3): mp3-mid -> mp3 close ✓
// No same-window read/stage touches the same region (checked pairwise).
// Gate ledger: 4 outstanding entering mp1; +4/phase; 12 at each gate;
// vmcnt(4) drains 8 = exactly the buffer read after the gate BAR.
// Prologue: buf0 full (8 loads) + {A1.mh0,B1.nh1}(k1) (4); vmcnt(4) -> buf0
// complete, leaves 4 = steady-state entry set.
__global__ __launch_bounds__(512, 2)
void k_gemm8(const signed char* __restrict__ Aq,   // [4096][4096]  (M x K)
             const signed char* __restrict__ Bq,   // [16384][4096] (N x K)
             const float* __restrict__ sx,
             const float* __restrict__ scales,
             float* __restrict__ C) {
    __shared__ __align__(16) signed char lds[131072];

    const int tid  = threadIdx.x;
    const int lane = tid & 63;
    const int wid  = tid >> 6;
    const int l15  = lane & 15;
    const int qg   = lane >> 4;
    const int swz  = l15 & 7;

    // XCD-bijective swizzle (nwg=1024 % 8 == 0) + supergroup-of-8-pm mapping
    const int bid = blockIdx.x;
    const int wg  = (bid & 7) * 128 + (bid >> 3);
    const int gidx   = wg >> 9;
    const int within = wg & 511;
    const int pm = gidx * 8 + (within & 7);   // [0,16)
    const int pn = within >> 3;               // [0,64)

    const int wm = (wid >> 2) * 128;
    const int wn = (wid & 3) * 64;

    // staging: per-lane pre-swizzled source offset (lane l covers row r0+(l>>3),
    // chunk l&7 -> source chunk (l&7)^(l>>3))
    const int l3 = lane >> 3, l7 = lane & 7;
    const int lane_off = l3 * K_DIM + ((l7 ^ l3) << 4);
    const signed char* Asrc = Aq + (size_t)(pm * 256) * K_DIM + lane_off;
    const signed char* Bsrc = Bq + (size_t)(pn * 256) * K_DIM + lane_off;
    const int ar0 = wid * 8;
    const int br0 = (wid >> 2) * 64 + (wid & 3) * 8;

    auto stageA = [&](int buf, int mh, int kt) {
        const int r0 = mh * 64 + ar0;
        const signed char* s = Asrc + (size_t)r0 * K_DIM + kt * 128;
        signed char* d = lds + buf * 65536 + r0 * 128;
        gload16(s, d);
        gload16(s + (size_t)128 * K_DIM, d + 128 * 128);
    };
    auto stageB = [&](int buf, int nh, int kt) {
        const int r0 = nh * 32 + br0;
        const signed char* s = Bsrc + (size_t)r0 * K_DIM + kt * 128;
        signed char* d = lds + buf * 65536 + 32768 + r0 * 128;
        gload16(s, d);
        gload16(s + (size_t)128 * K_DIM, d + 128 * 128);
    };

    i32x4 acc[8][4];
    #pragma unroll
    for (int a = 0; a < 8; ++a)
        #pragma unroll
        for (int b = 0; b < 4; ++b)
            acc[a][b] = (i32x4){0, 0, 0, 0};

    i32x4 af[8], bf[4];
    auto ldA = [&](int buf, int mh) {
        const signed char* base = lds + buf * 65536;
        #pragma unroll
        for (int fm = 0; fm < 4; ++fm) {
            const int ro = (wm + mh * 64 + fm * 16 + l15) * 128;
            #pragma unroll
            for (int ks = 0; ks < 2; ++ks)
                af[fm * 2 + ks] = *(const i32x4*)(base + ro + (((ks * 4 + qg) ^ swz) << 4));
        }
    };
    auto ldB = [&](int buf, int nh) {
        const signed char* base = lds + buf * 65536 + 32768;
        #pragma unroll
        for (int fn = 0; fn < 2; ++fn) {
            const int ro = (wn + nh * 32 + fn * 16 + l15) * 128;
            #pragma unroll
            for (int ks = 0; ks < 2; ++ks)
                bf[fn * 2 + ks] = *(const i32x4*)(base + ro + (((ks * 4 + qg) ^ swz) << 4));
        }
    };
    auto mma = [&](int mh, int nh) {
        #pragma unroll
        for (int ks = 0; ks < 2; ++ks)
            #pragma unroll
            for (int fm = 0; fm < 4; ++fm)
                #pragma unroll
                for (int fn = 0; fn < 2; ++fn)
                    acc[mh * 4 + fm][nh * 2 + fn] = __builtin_amdgcn_mfma_i32_16x16x64_i8(
                        af[fm * 2 + ks], bf[fn * 2 + ks], acc[mh * 4 + fm][nh * 2 + fn], 0, 0, 0);
    };

    // ---- prologue: buf0 full (k0) + {A1.mh0, B1.nh1}(k1) ----
    stageB(0, 0, 0); stageB(0, 1, 0); stageA(0, 0, 0); stageA(0, 1, 0);
    stageA(1, 0, 1); stageB(1, 1, 1);
    VM4();   // 12 outstanding -> drain 8 = buf0 complete; leaves 4 (k1 partial)
    BAR();

    // ---- main loop: 16 iters x 2 K-tiles ----
    for (int t = 0; t < 16; ++t) {
        const int k1 = 2 * t + 1;          // buf1 tile this iter
        const int k2 = (2 * t + 2) & 31;   // wrap: harmless garbage stage
        const int k3 = (2 * t + 3) & 31;

        // mp1: clusters (0,0),(0,1) on buf0
        ldA(0, 0); ldB(0, 0);
        stageB(1, 0, k1); stageA(1, 1, k1);
        BAR();
        PRIO1(); mma(0, 0); PRIO0(); SCHED0();
        ldB(0, 1); SCHED0();
        PRIO1(); mma(0, 1); PRIO0(); SCHED0();
        BAR();
        // mp2: clusters (1,1),(1,0) on buf0 | GATE -> buf1 (k1)
        ldA(0, 1);
        stageA(0, 0, k2); stageB(0, 1, k2);
        BAR();
        PRIO1(); mma(1, 1); PRIO0(); SCHED0();
        ldB(0, 0); SCHED0();
        PRIO1(); mma(1, 0); PRIO0(); SCHED0();
        VM4();
        BAR();
        // mp3: clusters (0,0),(0,1) on buf1
        ldA(1, 0); ldB(1, 0);
        stageA(0, 1, k2); stageB(0, 0, k2);
        BAR();
        PRIO1(); mma(0, 0); PRIO0(); SCHED0();
        ldB(1, 1); SCHED0();
        PRIO1(); mma(0, 1); PRIO0(); SCHED0();
        BAR();
        // mp4: clusters (1,1),(1,0) on buf1 | GATE -> buf0 (k2)
        ldA(1, 1);
        stageA(1, 0, k3); stageB(1, 1, k3);
        BAR();
        PRIO1(); mma(1, 1); PRIO0(); SCHED0();
        ldB(1, 0); SCHED0();
        PRIO1(); mma(1, 0); PRIO0(); SCHED0();
        VM4();
        BAR();
    }
    asm volatile("s_waitcnt vmcnt(0)" ::: "memory");  // drain tail garbage stages

    // ---- epilogue: C/D frag: col=lane&15, row=(lane>>4)*4+reg ----
    const float sw = scales[0];
    const int gn0 = pn * 256 + wn + l15;
    const int rb  = (lane >> 4) * 4;
    #pragma unroll
    for (int mi = 0; mi < 8; ++mi) {
        const int rowoff = (mi >> 2) * 64 + (mi & 3) * 16;
        #pragma unroll
        for (int r = 0; r < 4; ++r) {
            const int gm = pm * 256 + wm + rowoff + rb + r;
            const float s = sx[gm] * sw;
            float* crow = C + (size_t)gm * N_DIM + gn0;
            #pragma unroll
            for (int ni = 0; ni < 4; ++ni)
                crow[(ni >> 1) * 32 + (ni & 1) * 16] = (float)acc[mi][ni][r] * s;
        }
    }
}

extern "C" void kernel_launch(void* const* d_in, const int* in_sizes, int n_in,
                              void* d_out, int out_size, void* d_ws, size_t ws_size,
                              hipStream_t stream) {
    const float* x = (const float*)d_in[0];   // (2,2048,4096) f32
    const float* w = (const float*)d_in[1];   // (16384,4096) f32
    float* out = (float*)d_out;               // (2,2048,16384) f32
    char* ws = (char*)d_ws;

    float*  scales = (float*)(ws);                     // 2 floats
    double* part   = (double*)(ws + 1024);             // 2048 doubles
    float*  sx     = (float*)(ws + 32 * 1024);         // 4096 floats
    signed char* xq = (signed char*)(ws + 64 * 1024);  // 16 MiB
    signed char* wq = xq + (size_t)M_ROWS * K_DIM;     // 64 MiB

    k_abs_partial<<<2048, 256, 0, stream>>>((const float4*)w, part);
    k_abs_final<<<1, 256, 0, stream>>>(part, scales);
    k_wquant<<<8192, 256, 0, stream>>>((const float4*)w, scales, (char4*)wq);
    k_xquant<<<M_ROWS, 256, 0, stream>>>((const float4*)x, (char4*)xq, sx);
    k_gemm8<<<(M_ROWS / 256) * (N_DIM / 256), 512, 0, stream>>>(xq, wq, sx, scales, out);
}